// Round 6
// baseline (592.812 us; speedup 1.0000x reference)
//
#include <hip/hip_runtime.h>
#include <hip/hip_bf16.h>
#include <hip/hip_cooperative_groups.h>

namespace cg = cooperative_groups;

// Problem constants
#define BATCH   4096
#define HIDDEN  128
#define SESS    50
#define KTOT    4096
#define NB      ((size_t)BATCH * HIDDEN)

// GEMM phase tiling: block = 16 rows x 64 cols x full K; BK=128 per LDS tile.
#define BK      128
#define NT      (KTOT / BK)          // 32
#define ABY     8192                 // 16 rows * 128 k * 4B
#define BBY     16384                // 128 k * 64 cols * 2B
#define BUF     (ABY + BBY)          // 24576; x3 = 73728 B LDS (2 blocks/CU)

typedef __bf16 bf16x8 __attribute__((ext_vector_type(8)));
typedef __bf16 bf16x4 __attribute__((ext_vector_type(4)));
typedef float  f32x4  __attribute__((ext_vector_type(4)));
typedef float  f32x2  __attribute__((ext_vector_type(2)));

__device__ __forceinline__ f32x4 mfma_bf16(bf16x8 a, bf16x8 b, f32x4 c) {
    return __builtin_amdgcn_mfma_f32_16x16x32_bf16(a, b, c, 0, 0, 0);
}

// Async global->LDS, 16B/lane. LDS dest = wave-uniform base (+lane*16 by HW);
// global src is per-lane (swizzles live on the source side). Tracked by vmcnt.
__device__ __forceinline__ void gload16(const void* g, void* l) {
    __builtin_amdgcn_global_load_lds(
        (const __attribute__((address_space(1))) void*)g,
        (__attribute__((address_space(3))) void*)l, 16, 0, 0);
}

// Packed B layout (BYTES), XOR-swizzled for conflict-free ds_read_b128:
//   elem(k,h) -> (k>>3)*2048 + [ (h>>4)*256 + (h&15)*16 + (k&7)*2 ] ^ (((k>>3)&3)<<4)
// XOR key is bits 4-5 only -> the (h>>4)*256 field and (k&7)*2 field are
// unaffected; an n-half (64 cols) of a chunk is the contiguous 1024B at
// +nb*1024. A-tile LDS: [16 rows][512B]; within-row byte w holds global byte
// w ^ ((row&7)<<4) (16B-granule involution on both stage and read sides).

// ---------------------------------------------------------------------------
// GEMM phase body (shared by phases 2 and 3): C[16x64] = X[16rows x 4096] @
// Bp[4096 x 64cols(nb)]. Triple-buffered BK=128 tiles, depth-2 prefetch,
// counted vmcnt(12/6/0) (6 gload/wave/tile: 2 A + 4 B), raw s_barrier,
// pure ds_read+cvt+MFMA K-loop. Wave w owns n-frag w (16 cols), full M/K.
// C/D layout: row = quad*4 + reg, col = lane&15 [HW-verified m89/m91].
// PHASE 2: packed-bf16 store into TTp. PHASE 3: fp32 store into Rf.
// ---------------------------------------------------------------------------
template <int PHASE>
__device__ __forceinline__ void gemm_block(const float* __restrict__ X,
                                           const char* __restrict__ Bp,
                                           char* lds, int tid, int blk,
                                           __bf16* TTp, float* Rf) {
    const int w    = tid >> 6;
    const int lane = tid & 63;
    const int lo   = lane & 15;
    const int quad = lane >> 4;
    const int mb   = blk >> 1;
    const int nb   = blk & 1;
    const int rowBase = mb * 16;
    const int akey = (lo & 7) << 4;
    f32x4 acc = {0.f, 0.f, 0.f, 0.f};

#define STG(t_, dst_) do {                                                   \
    _Pragma("unroll")                                                        \
    for (int ai_ = 0; ai_ < 2; ++ai_) {                                      \
        const int rl_ = 4 * w + 2 * ai_ + (lane >> 5);                       \
        gload16((const char*)X +                                             \
                    ((size_t)(rowBase + rl_) * KTOT + (size_t)(t_) * BK) * 4 \
                    + (((lane & 31) * 16) ^ ((rl_ & 7) << 4)),               \
                (dst_) + (4 * w + 2 * ai_) * 512);                           \
    }                                                                        \
    _Pragma("unroll")                                                        \
    for (int bi_ = 0; bi_ < 4; ++bi_) {                                      \
        const int c_ = 4 * w + bi_;                                          \
        gload16(Bp + ((size_t)(t_) * 16 + c_) * 2048 + nb * 1024 +           \
                    lane * 16,                                               \
                (dst_) + ABY + c_ * 1024);                                   \
    }                                                                        \
} while (0)

#define KTL(cb_) do {                                                        \
    const char* Ar_ = (cb_) + lo * 512;                                      \
    const char* Bb_ = (cb_) + ABY + quad * 1024 + w * 256 +                  \
                      ((lo * 16) ^ (quad << 4));                             \
    _Pragma("unroll")                                                        \
    for (int ks_ = 0; ks_ < 4; ++ks_) {                                      \
        const f32x4 a0_ =                                                    \
            *(const f32x4*)(Ar_ + ((ks_ * 128 + quad * 32) ^ akey));         \
        const f32x4 a1_ =                                                    \
            *(const f32x4*)(Ar_ + ((ks_ * 128 + quad * 32 + 16) ^ akey));    \
        const bf16x8 b_ = *(const bf16x8*)(Bb_ + ks_ * 4096);                \
        bf16x8 af_;                                                          \
        af_[0] = (__bf16)a0_[0]; af_[1] = (__bf16)a0_[1];                    \
        af_[2] = (__bf16)a0_[2]; af_[3] = (__bf16)a0_[3];                    \
        af_[4] = (__bf16)a1_[0]; af_[5] = (__bf16)a1_[1];                    \
        af_[6] = (__bf16)a1_[2]; af_[7] = (__bf16)a1_[3];                    \
        acc = mfma_bf16(af_, b_, acc);                                       \
    }                                                                        \
} while (0)

    STG(0, lds);
    STG(1, lds + BUF);
    char* cb = lds;               // compute buffer (tile t)
    char* sb = lds + 2 * BUF;     // stage buffer   (tile t+2)
    for (int t = 0; t < NT; ++t) {
        if (t + 2 < NT) STG(t + 2, sb);
        if (t < NT - 2)
            asm volatile("s_waitcnt vmcnt(12)" ::: "memory");
        else if (t == NT - 2)
            asm volatile("s_waitcnt vmcnt(6)" ::: "memory");
        else
            asm volatile("s_waitcnt vmcnt(0)" ::: "memory");
        __builtin_amdgcn_s_barrier();        // all waves' tile-t staging done
        __builtin_amdgcn_sched_barrier(0);
        KTL(cb);
        __builtin_amdgcn_s_barrier();        // reads done before restage
        __builtin_amdgcn_sched_barrier(0);
        cb += BUF; if (cb == lds + 3 * BUF) cb = lds;
        sb += BUF; if (sb == lds + 3 * BUF) sb = lds;
    }
#undef STG
#undef KTL

    if constexpr (PHASE == 2) {
        // Packed store: chunk = rowBase/8 + quad/2; k&7 = (quad&1)*4 + r ->
        // 4 acc regs are 4 consecutive packed bf16 (8B store, below XOR bits).
        const long chunk = (rowBase >> 3) + (quad >> 1);
        const int  swz   = (int)((chunk & 3) << 4);
        char* tb = (char*)TTp + chunk * 2048 + (quad & 1) * 8;
        bf16x4 p;
#pragma unroll
        for (int r = 0; r < 4; ++r) p[r] = (__bf16)acc[r];
        *(bf16x4*)(tb + ((nb * 1024 + w * 256 + lo * 16) ^ swz)) = p;
    } else {
        float* op = Rf + (size_t)(rowBase + quad * 4) * HIDDEN +
                    (nb * 4 + w) * 16 + lo;
#pragma unroll
        for (int r = 0; r < 4; ++r) op[(size_t)r * HIDDEN] = acc[r];
    }
}

// ---------------------------------------------------------------------------
// MEGA kernel (cooperative, 1 dispatch): gather -> T=A@E (packed) -> R=D@T ->
// row-normalize. 512 blocks x 256 thr = 2 blocks/CU co-resident (LDS 72KB,
// 2x72=144KB <= 160KB). grid.sync() + device fence between phases.
// ---------------------------------------------------------------------------
__global__ __launch_bounds__(256, 2)
void mega_kernel(const float* __restrict__ emb,
                 const int* __restrict__ items32,
                 const float* __restrict__ Amat,
                 const float* __restrict__ Dmat,
                 __bf16* __restrict__ ETp,
                 __bf16* __restrict__ TTp,
                 float* __restrict__ Rf,
                 float* __restrict__ out) {
    __shared__ __align__(16) char lds[3 * BUF];   // 73728 B
    const int tid  = threadIdx.x;
    const int blk  = blockIdx.x;
    const int w    = tid >> 6;
    const int lane = tid & 63;
    cg::grid_group grid = cg::this_grid();

    // ---- Phase 1: gather. 8 rows/block, 2 rows/wave, 25 indep loads/lane.
    {
        int* sidx = (int*)lds;                     // [8][SESS]
        const int b0 = blk * 8;
        const bool is64 = (items32[1] | items32[3] | items32[5] | items32[7] |
                           items32[9] | items32[11] | items32[13] |
                           items32[15]) == 0;
        for (int i = tid; i < 8 * SESS; i += 256)
            sidx[i] = is64
                ? (int)((const long long*)items32)[(long)b0 * SESS + i]
                : items32[b0 * SESS + i];
        __syncthreads();
        const int c  = lane & 31;
        const int hh = lane >> 5;
#pragma unroll
        for (int rr = 0; rr < 2; ++rr) {
            const int rloc = w * 2 + rr;
            f32x4 acc = {0.f, 0.f, 0.f, 0.f};
#pragma unroll
            for (int i = 0; i < 25; ++i)
                acc += *(const f32x4*)(emb +
                        (long)sidx[rloc * SESS + hh + 2 * i] * HIDDEN + c * 4);
#pragma unroll
            for (int j = 0; j < 4; ++j) acc[j] += __shfl_xor(acc[j], 32, 64);
            if (hh == 0) {
                const int  b     = b0 + rloc;
                const long chunk = b >> 3;
                const int  swz   = (int)((chunk & 3) << 4);
                char* basep = (char*)ETp + chunk * 2048 + (b & 7) * 2;
                const int hi4 = (c >> 2) * 256;
#pragma unroll
                for (int j = 0; j < 4; ++j) {
                    const int hl = 4 * (c & 3) + j;
                    *(__bf16*)(basep + ((hi4 + hl * 16) ^ swz)) =
                        (__bf16)acc[j];
                }
            }
        }
        __threadfence();
    }
    grid.sync();

    // ---- Phase 2: T = A @ E  (packed bf16 out)
    gemm_block<2>(Amat, (const char*)ETp, lds, tid, blk, TTp, nullptr);
    __threadfence();
    grid.sync();

    // ---- Phase 3: R = D @ T  (fp32 out)
    gemm_block<3>(Dmat, (const char*)TTp, lds, tid, blk, nullptr, Rf);
    __threadfence();
    grid.sync();

    // ---- Phase 4: row L2-normalize. 8 rows/block, 2 rows/wave.
#pragma unroll
    for (int rr = 0; rr < 2; ++rr) {
        const int row = blk * 8 + w * 2 + rr;
        const size_t base = (size_t)row * HIDDEN + lane * 2;
        f32x2 v = *(const f32x2*)(Rf + base);
        float sq = v[0] * v[0] + v[1] * v[1];
#pragma unroll
        for (int m = 1; m < 64; m <<= 1) sq += __shfl_xor(sq, m, 64);
        const float s = rsqrtf(sq);
        f32x2 o = {v[0] * s, v[1] * s};
        *(f32x2*)(out + base) = o;
    }
}

// ---------------------------------------------------------------------------
// out = normalize_rows( D @ (A @ E) )  — ONE cooperative dispatch.
// ws: ETp 1MB | TTp 1MB | Rf 2MB  (~4 MB)
// ---------------------------------------------------------------------------
extern "C" void kernel_launch(void* const* d_in, const int* in_sizes, int n_in,
                              void* d_out, int out_size, void* d_ws, size_t ws_size,
                              hipStream_t stream) {
    const float* emb   = (const float*)d_in[0];
    const int*   items = (const int*)d_in[1];
    const float* A     = (const float*)d_in[2];
    const float* D     = (const float*)d_in[3];
    float* out = (float*)d_out;

    __bf16* ETp = (__bf16*)d_ws;
    __bf16* TTp = ETp + NB;
    float*  Rf  = (float*)(TTp + NB);

    void* args[] = { (void*)&emb, (void*)&items, (void*)&A, (void*)&D,
                     (void*)&ETp, (void*)&TTp, (void*)&Rf, (void*)&out };
    hipLaunchCooperativeKernel((void*)mega_kernel, dim3(512), dim3(256),
                               args, 0, stream);
}

// Round 7
// 220.757 us; speedup vs baseline: 2.6854x; 2.6854x over previous
//
#include <hip/hip_runtime.h>
#include <hip/hip_bf16.h>

// Problem constants
#define BATCH   4096
#define HIDDEN  128
#define SESS    50
#define KTOT    4096
#define NB      ((size_t)BATCH * HIDDEN)

// GEMM tiling: block = 16 rows x 64 cols (nb half) x full K; BK=128 per tile.
#define BK      128
#define NT      (KTOT / BK)          // 32
#define ABY     8192                 // 16 rows * 128 k * 4B
#define BBY     16384                // 128 k * 64 cols * 2B
#define BUF     (ABY + BBY)          // 24576; x3 = 73728 B LDS -> 2 blocks/CU

typedef __bf16 bf16x8 __attribute__((ext_vector_type(8)));
typedef __bf16 bf16x4 __attribute__((ext_vector_type(4)));
typedef float  f32x4  __attribute__((ext_vector_type(4)));
typedef float  f32x2  __attribute__((ext_vector_type(2)));

__device__ __forceinline__ f32x4 mfma_bf16(bf16x8 a, bf16x8 b, f32x4 c) {
    return __builtin_amdgcn_mfma_f32_16x16x32_bf16(a, b, c, 0, 0, 0);
}

// Async global->LDS, 16B/lane. LDS dest = wave-uniform base (+lane*16 by HW);
// global src is per-lane (swizzles live on the source side). Tracked by vmcnt.
__device__ __forceinline__ void gload16(const void* g, void* l) {
    __builtin_amdgcn_global_load_lds(
        (const __attribute__((address_space(1))) void*)g,
        (__attribute__((address_space(3))) void*)l, 16, 0, 0);
}

// Packed B layout (BYTES), XOR-swizzled for conflict-free ds_read_b128:
//   elem(k,h) -> (k>>3)*2048 + [ (h>>4)*256 + (h&15)*16 + (k&7)*2 ] ^ (((k>>3)&3)<<4)
// XOR key is bits 4-5 only -> nb-halves (64 cols) of a chunk stay contiguous
// 1024B at +nb*1024. A-tile LDS: [16 rows][512B]; within-row byte w holds
// global byte w ^ ((row&7)<<4) (16B-granule involution, stage & read sides).

// ---------------------------------------------------------------------------
// Gather: E[b][h] = sum_s emb[items[b][s]][h] -> packed bf16 ETp (layout above).
// 1024 blocks x 256 thr, tiny LDS -> 32 waves/CU (R3-proven).
// ---------------------------------------------------------------------------
__global__ __launch_bounds__(256)
void gather_sum_kernel(const float* __restrict__ emb,
                       const int* __restrict__ items32,
                       __bf16* __restrict__ ETp) {
    __shared__ int sidx[4][SESS];
    const int t  = threadIdx.x;
    const int b0 = blockIdx.x * 4;
    const bool is64 = (items32[1] | items32[3] | items32[5] | items32[7] |
                       items32[9] | items32[11] | items32[13] | items32[15]) == 0;
    if (t < 4 * SESS) {
        const int w_ = t / SESS, s_ = t % SESS;
        sidx[w_][s_] = is64
            ? (int)((const long long*)items32)[(long)(b0 + w_) * SESS + s_]
            : items32[(b0 + w_) * SESS + s_];
    }
    __syncthreads();
    const int w    = t >> 6;
    const int lane = t & 63;
    const int c    = lane & 31;
    const int h    = lane >> 5;
    f32x4 acc = {0.f, 0.f, 0.f, 0.f};
#pragma unroll
    for (int i = 0; i < 25; ++i) {
        acc += *(const f32x4*)(emb + (long)sidx[w][h + 2 * i] * HIDDEN + c * 4);
    }
#pragma unroll
    for (int j = 0; j < 4; ++j) acc[j] += __shfl_xor(acc[j], 32, 64);
    if (h == 0) {
        const int  b     = b0 + w;
        const long chunk = b >> 3;
        const int  swz   = (int)((chunk & 3) << 4);
        char* basep = (char*)ETp + chunk * 2048 + (b & 7) * 2;
        const int hi4 = (c >> 2) * 256;          // (h>>4)*256
#pragma unroll
        for (int j = 0; j < 4; ++j) {
            const int hl = 4 * (c & 3) + j;      // h&15
            *(__bf16*)(basep + ((hi4 + hl * 16) ^ swz)) = (__bf16)acc[j];
        }
    }
}

// ---------------------------------------------------------------------------
// GEMM v8 (occupancy x2): C[16 x 64] = X[16 rows x 4096] @ Bp[4096 x 64(nb)].
// grid 512 x 256thr = 2 blocks/CU, 8 waves/CU (was 4). blk = nb*256 + mb so
// the A-sharing pair (mb,0),(mb,1) is 256 apart -> same XCD under round-robin
// -> second A read is an L2 hit. Triple-buffered BK=128 tiles, depth-2
// prefetch, counted vmcnt(12/6/0) (6 gloads/wave/tile: 2 A + 4 B), raw
// s_barrier, pure ds_read+cvt+MFMA K-loop. Wave w owns n-frag w (16 cols).
// C/D layout: row = quad*4 + reg, col = lane&15 [HW-verified m89/m91].
// PHASE 1: packed-bf16 store into TTp. PHASE 2: fp32 store into Rf.
// (Addressing identical to R6's gemm_block, which passed correctness.)
// ---------------------------------------------------------------------------
template <int PHASE>
__global__ __launch_bounds__(256, 2)
void gemm_mfma_kernel(const float* __restrict__ X,
                      const char* __restrict__ Bp,
                      __bf16* __restrict__ TTp,
                      float* __restrict__ Rf) {
    __shared__ __align__(16) char lds[3 * BUF];   // 73728 B
    const int tid  = threadIdx.x;
    const int w    = tid >> 6;
    const int lane = tid & 63;
    const int lo   = lane & 15;
    const int quad = lane >> 4;
    const int mb   = blockIdx.x & 255;
    const int nb   = blockIdx.x >> 8;
    const int rowBase = mb * 16;
    const int akey = (lo & 7) << 4;
    f32x4 acc = {0.f, 0.f, 0.f, 0.f};

#define STG(t_, dst_) do {                                                   \
    _Pragma("unroll")                                                        \
    for (int ai_ = 0; ai_ < 2; ++ai_) {                                      \
        const int rl_ = 4 * w + 2 * ai_ + (lane >> 5);                       \
        gload16((const char*)X +                                             \
                    ((size_t)(rowBase + rl_) * KTOT + (size_t)(t_) * BK) * 4 \
                    + (((lane & 31) * 16) ^ ((rl_ & 7) << 4)),               \
                (dst_) + (4 * w + 2 * ai_) * 512);                           \
    }                                                                        \
    _Pragma("unroll")                                                        \
    for (int bi_ = 0; bi_ < 4; ++bi_) {                                      \
        const int c_ = 4 * w + bi_;                                          \
        gload16(Bp + ((size_t)(t_) * 16 + c_) * 2048 + nb * 1024 +           \
                    lane * 16,                                               \
                (dst_) + ABY + c_ * 1024);                                   \
    }                                                                        \
} while (0)

#define KTL(cb_) do {                                                        \
    const char* Ar_ = (cb_) + lo * 512;                                      \
    const char* Bb_ = (cb_) + ABY + quad * 1024 + w * 256 +                  \
                      ((lo * 16) ^ (quad << 4));                             \
    _Pragma("unroll")                                                        \
    for (int ks_ = 0; ks_ < 4; ++ks_) {                                      \
        const f32x4 a0_ =                                                    \
            *(const f32x4*)(Ar_ + ((ks_ * 128 + quad * 32) ^ akey));         \
        const f32x4 a1_ =                                                    \
            *(const f32x4*)(Ar_ + ((ks_ * 128 + quad * 32 + 16) ^ akey));    \
        const bf16x8 b_ = *(const bf16x8*)(Bb_ + ks_ * 4096);                \
        bf16x8 af_;                                                          \
        af_[0] = (__bf16)a0_[0]; af_[1] = (__bf16)a0_[1];                    \
        af_[2] = (__bf16)a0_[2]; af_[3] = (__bf16)a0_[3];                    \
        af_[4] = (__bf16)a1_[0]; af_[5] = (__bf16)a1_[1];                    \
        af_[6] = (__bf16)a1_[2]; af_[7] = (__bf16)a1_[3];                    \
        acc = mfma_bf16(af_, b_, acc);                                       \
    }                                                                        \
} while (0)

    STG(0, lds);
    STG(1, lds + BUF);
    char* cb = lds;               // compute buffer (tile t)
    char* sb = lds + 2 * BUF;     // stage buffer   (tile t+2)
    for (int t = 0; t < NT; ++t) {
        if (t + 2 < NT) STG(t + 2, sb);
        if (t < NT - 2)
            asm volatile("s_waitcnt vmcnt(12)" ::: "memory");
        else if (t == NT - 2)
            asm volatile("s_waitcnt vmcnt(6)" ::: "memory");
        else
            asm volatile("s_waitcnt vmcnt(0)" ::: "memory");
        __builtin_amdgcn_s_barrier();        // all waves' tile-t staging done
        __builtin_amdgcn_sched_barrier(0);
        KTL(cb);
        __builtin_amdgcn_s_barrier();        // reads done before restage
        __builtin_amdgcn_sched_barrier(0);
        cb += BUF; if (cb == lds + 3 * BUF) cb = lds;
        sb += BUF; if (sb == lds + 3 * BUF) sb = lds;
    }
#undef STG
#undef KTL

    if constexpr (PHASE == 1) {
        // Packed store: chunk = rowBase/8 + quad/2; k&7 = (quad&1)*4 + r ->
        // 4 acc regs are 4 consecutive packed bf16 (8B store, below XOR bits).
        const long chunk = (rowBase >> 3) + (quad >> 1);
        const int  swz   = (int)((chunk & 3) << 4);
        char* tb = (char*)TTp + chunk * 2048 + (quad & 1) * 8;
        bf16x4 p;
#pragma unroll
        for (int r = 0; r < 4; ++r) p[r] = (__bf16)acc[r];
        *(bf16x4*)(tb + ((nb * 1024 + w * 256 + lo * 16) ^ swz)) = p;
    } else {
        float* op = Rf + (size_t)(rowBase + quad * 4) * HIDDEN +
                    (nb * 4 + w) * 16 + lo;
#pragma unroll
        for (int r = 0; r < 4; ++r) op[(size_t)r * HIDDEN] = acc[r];
    }
}

// ---------------------------------------------------------------------------
// norm: out[row] = Rf[row] / ||Rf[row]||. One wave per row, 2 floats/lane,
// 6-step shfl_xor reduce. 1024 blocks -> high occupancy, ~4 MB traffic.
// ---------------------------------------------------------------------------
__global__ __launch_bounds__(256)
void norm_kernel(const float* __restrict__ Rf, float* __restrict__ out) {
    const int t    = threadIdx.x;
    const int w    = t >> 6;
    const int lane = t & 63;
    const int row  = blockIdx.x * 4 + w;
    const size_t base = (size_t)row * HIDDEN + lane * 2;
    const f32x2 v = *(const f32x2*)(Rf + base);
    float sq = v[0] * v[0] + v[1] * v[1];
#pragma unroll
    for (int m = 1; m < 64; m <<= 1) sq += __shfl_xor(sq, m, 64);
    const float s = rsqrtf(sq);
    f32x2 o = {v[0] * s, v[1] * s};
    *(f32x2*)(out + base) = o;
}

// ---------------------------------------------------------------------------
// out = normalize_rows( D @ (A @ E) )
// 4 dispatches: gather -> gemm<1> (packed TTp) -> gemm<2> (fp32 Rf) -> norm.
// ws: ETp 1MB | TTp 1MB | Rf 2MB  (~4 MB)
// ---------------------------------------------------------------------------
extern "C" void kernel_launch(void* const* d_in, const int* in_sizes, int n_in,
                              void* d_out, int out_size, void* d_ws, size_t ws_size,
                              hipStream_t stream) {
    const float* emb   = (const float*)d_in[0];
    const int*   items = (const int*)d_in[1];
    const float* A     = (const float*)d_in[2];
    const float* D     = (const float*)d_in[3];
    float* out = (float*)d_out;

    __bf16* ETp = (__bf16*)d_ws;
    __bf16* TTp = ETp + NB;
    float*  Rf  = (float*)(TTp + NB);

    gather_sum_kernel<<<BATCH / 4, 256, 0, stream>>>(emb, items, ETp);
    gemm_mfma_kernel<1><<<512, 256, 0, stream>>>(A, (const char*)ETp, TTp, nullptr);
    gemm_mfma_kernel<2><<<512, 256, 0, stream>>>(D, (const char*)TTp, nullptr, Rf);
    norm_kernel<<<BATCH / 4, 256, 0, stream>>>(Rf, out);
}

// Round 8
// 214.991 us; speedup vs baseline: 2.7574x; 1.0268x over previous
//
#include <hip/hip_runtime.h>
#include <hip/hip_bf16.h>

// Problem constants
#define BATCH   4096
#define HIDDEN  128
#define SESS    50
#define KTOT    4096
#define NB      ((size_t)BATCH * HIDDEN)

// GEMM tiling: block = 128 rows x 128 cols x K-eighth (512); BK=32 per tile.
#define MROWS   128
#define KSP     8                    // k-splits
#define KQL     512                  // k per split
#define BK      32
#define NTL     (KQL / BK)           // 16 tiles
#define ABY     16384                // 128 rows * 32 k * 4B
#define BBY     8192                 // 32 k * 128 cols * 2B
#define BUF     (ABY + BBY)          // 24576
#define NBUF    5                    // 122880 B LDS -> depth-4 prefetch

typedef __bf16 bf16x8 __attribute__((ext_vector_type(8)));
typedef float  f32x4  __attribute__((ext_vector_type(4)));
typedef float  f32x2  __attribute__((ext_vector_type(2)));

__device__ __forceinline__ f32x4 mfma_bf16(bf16x8 a, bf16x8 b, f32x4 c) {
    return __builtin_amdgcn_mfma_f32_16x16x32_bf16(a, b, c, 0, 0, 0);
}

// Async global->LDS, 16B/lane. LDS dest = wave-uniform base (+lane*16 by HW);
// global src is per-lane (swizzles live on the source side). Tracked by vmcnt.
__device__ __forceinline__ void gload16(const void* g, void* l) {
    __builtin_amdgcn_global_load_lds(
        (const __attribute__((address_space(1))) void*)g,
        (__attribute__((address_space(3))) void*)l, 16, 0, 0);
}

// Packed B layout (BYTES), XOR-swizzled for conflict-free ds_read_b128:
//   elem(k,h) -> (k>>3)*2048 + [ (h>>4)*256 + (h&15)*16 + (k&7)*2 ] ^ (((k>>3)&3)<<4)
// BK=32 tile = 4 consecutive chunks (8KB, chunk%4 == quad in-tile).
// A-tile LDS: [128 rows][128B]; within-row byte x holds global byte
// x ^ ((row&7)<<4)  (16B-granule involution on stage & read sides; ds_read
// spread: granule%8 = (lo&7)^(quad*2) -> 2 lanes/4-bank group = free).

// ---------------------------------------------------------------------------
// Gather: E[b][h] = sum_s emb[items[b][s]][h] -> packed bf16 ETp (layout above).
// 1024 blocks x 256 thr, tiny LDS -> 32 waves/CU (R3-proven).
// ---------------------------------------------------------------------------
__global__ __launch_bounds__(256)
void gather_sum_kernel(const float* __restrict__ emb,
                       const int* __restrict__ items32,
                       __bf16* __restrict__ ETp) {
    __shared__ int sidx[4][SESS];
    const int t  = threadIdx.x;
    const int b0 = blockIdx.x * 4;
    const bool is64 = (items32[1] | items32[3] | items32[5] | items32[7] |
                       items32[9] | items32[11] | items32[13] | items32[15]) == 0;
    if (t < 4 * SESS) {
        const int w_ = t / SESS, s_ = t % SESS;
        sidx[w_][s_] = is64
            ? (int)((const long long*)items32)[(long)(b0 + w_) * SESS + s_]
            : items32[(b0 + w_) * SESS + s_];
    }
    __syncthreads();
    const int w    = t >> 6;
    const int lane = t & 63;
    const int c    = lane & 31;
    const int h    = lane >> 5;
    f32x4 acc = {0.f, 0.f, 0.f, 0.f};
#pragma unroll
    for (int i = 0; i < 25; ++i) {
        acc += *(const f32x4*)(emb + (long)sidx[w][h + 2 * i] * HIDDEN + c * 4);
    }
#pragma unroll
    for (int j = 0; j < 4; ++j) acc[j] += __shfl_xor(acc[j], 32, 64);
    if (h == 0) {
        const int  b     = b0 + w;
        const long chunk = b >> 3;
        const int  swz   = (int)((chunk & 3) << 4);
        char* basep = (char*)ETp + chunk * 2048 + (b & 7) * 2;
        const int hi4 = (c >> 2) * 256;          // (h>>4)*256
#pragma unroll
        for (int j = 0; j < 4; ++j) {
            const int hl = 4 * (c & 3) + j;      // h&15
            *(__bf16*)(basep + ((hi4 + hl * 16) ^ swz)) = (__bf16)acc[j];
        }
    }
}

// ---------------------------------------------------------------------------
// GEMM v9 (deep-coverage): partial[kq] = X[128r x 512k] @ Bp[512k x 128].
// grid (32,8) x 256thr = 256 blocks, 1/CU. 5-buffer LDS ring, depth-4
// prefetch, ONE barrier/tile (stage(t+4) hits buf[t-1], finished by all
// waves before barrier t), counted vmcnt = min(18,(15-t)*6), never 0 until
// drain. Per tile/wave: 4 A-frags + 4 B-frags ds_read, 16 MFMAs (~450 cyc
// busy -> depth-4 covers ~2000 cyc of load latency).
// Wave w: m-half mh=w&1 (64 rows), n-half nh=w>>1 (64 cols); acc[4][4].
// C/D layout: row = quad*4 + reg, col = lane&15 [HW-verified m89/m91].
// fp32 partial out at Tp + kq*NB.
// ---------------------------------------------------------------------------
__global__ __launch_bounds__(256, 1)
void gemm_mfma_kernel(const float* __restrict__ X,
                      const char* __restrict__ Bpk,
                      float* __restrict__ Tp) {
    __shared__ __align__(16) char lds[NBUF * BUF];   // 122880 B
    const int tid  = threadIdx.x;
    const int w    = tid >> 6;
    const int lane = tid & 63;
    const int lo   = lane & 15;
    const int quad = lane >> 4;
    const int rowBase = blockIdx.x * MROWS;
    const int kq      = blockIdx.y;

    const int mh = w & 1;
    const int nh = w >> 1;
    const int akey = (lo & 7) << 4;
    const int bkey = quad << 4;

    // staging per tile: 16 A ops (1KB = 8 rows each) + 8 B ops (1KB each);
    // wave w -> A ops {4w..4w+3}, B ops {2w,2w+1}.
#define STG(t_, dst_) do {                                                   \
    _Pragma("unroll")                                                        \
    for (int ai_ = 0; ai_ < 4; ++ai_) {                                      \
        const int i_  = 4 * w + ai_;                                         \
        const int rl_ = 8 * i_ + (lane >> 3);     /* local row 0..127 */     \
        gload16((const char*)X +                                             \
                    ((size_t)(rowBase + rl_) * KTOT + kq * KQL +             \
                     (size_t)(t_) * BK) * 4 +                                \
                    ((((lane & 7) * 16)) ^ ((rl_ & 7) << 4)),                \
                (dst_) + i_ * 1024);                                         \
    }                                                                        \
    _Pragma("unroll")                                                        \
    for (int bi_ = 0; bi_ < 2; ++bi_) {                                      \
        const int j_ = 2 * w + bi_;                                          \
        gload16(Bpk + ((size_t)(kq * 64 + (t_) * 4 + (j_ >> 1))) * 2048 +    \
                    (j_ & 1) * 1024 + lane * 16,                             \
                (dst_) + ABY + j_ * 1024);                                   \
    }                                                                        \
} while (0)

    f32x4 acc[4][4];
#pragma unroll
    for (int i = 0; i < 4; ++i)
#pragma unroll
        for (int j = 0; j < 4; ++j) acc[i][j] = (f32x4){0.f, 0.f, 0.f, 0.f};

#define KTL(cb_) do {                                                        \
    const char* Ab_ = (cb_);                                                 \
    const char* Bb_ = (cb_) + ABY + quad * 2048;                             \
    bf16x8 af_[4];                                                           \
    _Pragma("unroll")                                                        \
    for (int fm_ = 0; fm_ < 4; ++fm_) {                                      \
        const int rr_ = (mh * 64 + fm_ * 16 + lo) * 128;                     \
        const f32x4 a0_ = *(const f32x4*)(Ab_ + rr_ + ((quad * 32) ^ akey)); \
        const f32x4 a1_ =                                                    \
            *(const f32x4*)(Ab_ + rr_ + ((quad * 32 + 16) ^ akey));          \
        af_[fm_][0] = (__bf16)a0_[0]; af_[fm_][1] = (__bf16)a0_[1];          \
        af_[fm_][2] = (__bf16)a0_[2]; af_[fm_][3] = (__bf16)a0_[3];          \
        af_[fm_][4] = (__bf16)a1_[0]; af_[fm_][5] = (__bf16)a1_[1];          \
        af_[fm_][6] = (__bf16)a1_[2]; af_[fm_][7] = (__bf16)a1_[3];          \
    }                                                                        \
    bf16x8 bf_[4];                                                           \
    _Pragma("unroll")                                                        \
    for (int fn_ = 0; fn_ < 4; ++fn_)                                        \
        bf_[fn_] = *(const bf16x8*)(Bb_ +                                    \
            ((((nh * 4 + fn_) * 256) + lo * 16) ^ bkey));                    \
    _Pragma("unroll")                                                        \
    for (int fm_ = 0; fm_ < 4; ++fm_)                                        \
        _Pragma("unroll")                                                    \
        for (int fn_ = 0; fn_ < 4; ++fn_)                                    \
            acc[fm_][fn_] = mfma_bf16(af_[fm_], bf_[fn_], acc[fm_][fn_]);    \
} while (0)

    // prologue: 4 tiles in flight (24 vmem ops/wave)
    STG(0, lds + 0 * BUF);
    STG(1, lds + 1 * BUF);
    STG(2, lds + 2 * BUF);
    STG(3, lds + 3 * BUF);

#pragma unroll
    for (int t = 0; t < NTL; ++t) {
        // wait own tile-t ops (oldest 6): min(18, (NTL-1-t)*6)
        if (t <= NTL - 4)
            asm volatile("s_waitcnt vmcnt(18)" ::: "memory");
        else if (t == NTL - 3)
            asm volatile("s_waitcnt vmcnt(12)" ::: "memory");
        else if (t == NTL - 2)
            asm volatile("s_waitcnt vmcnt(6)" ::: "memory");
        else
            asm volatile("s_waitcnt vmcnt(0)" ::: "memory");
        __builtin_amdgcn_s_barrier();     // all waves: tile-t staged, t-1 read
        __builtin_amdgcn_sched_barrier(0);
        if (t + 4 < NTL) STG(t + 4, lds + ((t + 4) % NBUF) * BUF);
        KTL(lds + (t % NBUF) * BUF);
        __builtin_amdgcn_sched_barrier(0);
    }
#undef STG
#undef KTL

    // fp32 partial: row = rowBase + mh*64 + fm*16 + quad*4 + r,
    //               col = nh*64 + fn*16 + lo  (16-lane coalesced rows)
    float* op = Tp + (size_t)kq * NB +
                (size_t)(rowBase + mh * 64) * HIDDEN + nh * 64;
#pragma unroll
    for (int fm = 0; fm < 4; ++fm)
#pragma unroll
        for (int r = 0; r < 4; ++r) {
            const int ro = (fm * 16 + quad * 4 + r) * HIDDEN;
#pragma unroll
            for (int fn = 0; fn < 4; ++fn)
                op[ro + fn * 16 + lo] = acc[fm][fn][r];
        }
}

// ---------------------------------------------------------------------------
// reduce8_pack: TTp(packed bf16) = sum of 8 k-split partials.
// ---------------------------------------------------------------------------
__global__ __launch_bounds__(256)
void reduce8_kernel(const float* __restrict__ Tp, __bf16* __restrict__ TTp) {
    const size_t i = ((size_t)blockIdx.x * 256 + threadIdx.x) * 4;
    f32x4 a = *(const f32x4*)(Tp + i);
#pragma unroll
    for (int p = 1; p < KSP; ++p) a += *(const f32x4*)(Tp + p * NB + i);
    const int  b     = (int)(i >> 7);
    const int  h0    = (int)(i & 127);
    const long chunk = b >> 3;
    const int  swz   = (int)((chunk & 3) << 4);
    char* basep = (char*)TTp + chunk * 2048 + (b & 7) * 2;
#pragma unroll
    for (int j = 0; j < 4; ++j) {
        const int h = h0 + j;
        *(__bf16*)(basep + (((h >> 4) * 256 + (h & 15) * 16) ^ swz)) =
            (__bf16)a[j];
    }
}

// ---------------------------------------------------------------------------
// rednorm8: out[row] = normalize(sum of 8 partials). One wave per row.
// ---------------------------------------------------------------------------
__global__ __launch_bounds__(256)
void rednorm8_kernel(const float* __restrict__ Tp, float* __restrict__ out) {
    const int t    = threadIdx.x;
    const int w    = t >> 6;
    const int lane = t & 63;
    const int row  = blockIdx.x * 4 + w;
    const size_t base = (size_t)row * HIDDEN + lane * 2;
    f32x2 v = *(const f32x2*)(Tp + base);
#pragma unroll
    for (int p = 1; p < KSP; ++p) v += *(const f32x2*)(Tp + p * NB + base);
    float sq = v[0] * v[0] + v[1] * v[1];
#pragma unroll
    for (int m = 1; m < 64; m <<= 1) sq += __shfl_xor(sq, m, 64);
    const float s = rsqrtf(sq);
    f32x2 o = {v[0] * s, v[1] * s};
    *(f32x2*)(out + base) = o;
}

// ---------------------------------------------------------------------------
// out = normalize_rows( D @ (A @ E) )
// 5 dispatches: gather -> gemm(A,E) 8 partials -> reduce8 (pack TTp) ->
// gemm(D,T) 8 partials -> rednorm8.
// ws: ETp 1MB | TTp 1MB | Tp fp32 x8 16MB  (~18 MB)
// ---------------------------------------------------------------------------
extern "C" void kernel_launch(void* const* d_in, const int* in_sizes, int n_in,
                              void* d_out, int out_size, void* d_ws, size_t ws_size,
                              hipStream_t stream) {
    const float* emb   = (const float*)d_in[0];
    const int*   items = (const int*)d_in[1];
    const float* A     = (const float*)d_in[2];
    const float* D     = (const float*)d_in[3];
    float* out = (float*)d_out;

    __bf16* ETp = (__bf16*)d_ws;
    __bf16* TTp = ETp + NB;
    float*  Tp  = (float*)(TTp + NB);

    gather_sum_kernel<<<BATCH / 4, 256, 0, stream>>>(emb, items, ETp);
    gemm_mfma_kernel<<<dim3(BATCH / MROWS, KSP), 256, 0, stream>>>(
        A, (const char*)ETp, Tp);
    reduce8_kernel<<<512, 256, 0, stream>>>(Tp, TTp);
    gemm_mfma_kernel<<<dim3(BATCH / MROWS, KSP), 256, 0, stream>>>(
        D, (const char*)TTp, Tp);
    rednorm8_kernel<<<BATCH / 4, 256, 0, stream>>>(Tp, out);
}